// Round 4
// baseline (633.548 us; speedup 1.0000x reference)
//
#include <hip/hip_runtime.h>
#include <hip/hip_fp16.h>
#include <stdint.h>

typedef unsigned int u32;
typedef unsigned long long u64;
typedef unsigned short ushort_t;

// Problem constants
#define B_ 8
#define C_ 256
#define L_ 2048
#define K_ 8192
#define M_ 16384   // B_*L_

// ---- workspace layout (bytes) ----  (WS_NEED = 25460992, proven to fit in rounds 2/3)
#define WS_KEYS   0            // u64[16384] -> 131072
#define WS_CNT    131072       // u32
#define WS_MAXCS  131076       // u32 (float bits, positive -> int cmp ok)
#define WS_LOSS   131080       // f32
#define WS_XSQ    131328       // f32[16384] -> 196864
#define WS_CSQ    196864       // f32[8192]  -> 229632
#define WS_LIST   295168       // u32[1M]    -> 4489472
#define WS_LMAX   4489472      // fp16[16384*256] -> 12878080
#define WS_XTH    12878080     // bf16[16384*256] -> 21266688
#define WS_CBH    21266688     // bf16[8192*256]  -> 25460992
#define LIST_CAP  1048576u

typedef __attribute__((ext_vector_type(8))) short s8v;   // 8 x bf16 (4 VGPR)
typedef __attribute__((ext_vector_type(4))) float f4v;

__device__ __forceinline__ ushort_t f2bf(float f) {
  u32 u = __float_as_uint(f);
  u32 r = (u + 0x7FFFu + ((u >> 16) & 1u)) >> 16;   // RN-even
  return (ushort_t)r;
}

__device__ __forceinline__ void gld16(void* lds, const void* g) {
  __builtin_amdgcn_global_load_lds(
      (const __attribute__((address_space(1))) u32*)g,
      (__attribute__((address_space(3))) u32*)lds, 16, 0, 0);
}

// ---------------- prep kernels ----------------

// transpose x (B,C,L) -> xt fp32 (M,C) [into emb out region] + bf16 (M,C) [ws]
__global__ void __launch_bounds__(256)
vq_transpose(const float* __restrict__ x, float* __restrict__ xtf,
             ushort_t* __restrict__ xth) {
  __shared__ float t[64][65];
  int tid = threadIdx.x;
  int b  = blockIdx.x >> 7;
  int cc = (blockIdx.x >> 5) & 3;
  int lc = blockIdx.x & 31;
#pragma unroll
  for (int j = 0; j < 4; ++j) {
    int c  = (tid >> 4) + j * 16;
    int lq = tid & 15;
    float4 v = *(const float4*)&x[((size_t)(b * C_ + cc * 64 + c)) * L_ + lc * 64 + lq * 4];
    t[c][lq * 4 + 0] = v.x; t[c][lq * 4 + 1] = v.y;
    t[c][lq * 4 + 2] = v.z; t[c][lq * 4 + 3] = v.w;
  }
  __syncthreads();
  int l = tid >> 2, qc = tid & 3;
  size_t m = (size_t)b * L_ + lc * 64 + l;
#pragma unroll
  for (int j = 0; j < 4; ++j) {
    int q = qc + j * 4;                    // float4 index 0..15
    float4 v = make_float4(t[q * 4 + 0][l], t[q * 4 + 1][l],
                           t[q * 4 + 2][l], t[q * 4 + 3][l]);
    *(float4*)&xtf[m * C_ + cc * 64 + q * 4] = v;
    ushort4 h;
    h.x = f2bf(v.x); h.y = f2bf(v.y); h.z = f2bf(v.z); h.w = f2bf(v.w);
    *(ushort4*)&xth[m * C_ + cc * 64 + q * 4] = h;
  }
}

// xsq from transposed fp32 rows (coalesced, deterministic order)
__global__ void vq_xsqt(const float* __restrict__ xtf, float* __restrict__ xsq) {
  int t = threadIdx.x;
  int m = blockIdx.x * 16 + (t >> 4);              // 1024 blocks
  int g = t & 15;
  const float* row = xtf + (size_t)m * C_;
  float s = 0.0f;
#pragma unroll
  for (int j = 0; j < 4; ++j) {
    float4 v = *(const float4*)&row[g * 4 + j * 64];
    s += v.x * v.x + v.y * v.y + v.z * v.z + v.w * v.w;
  }
#pragma unroll
  for (int off = 1; off < 16; off <<= 1) s += __shfl_xor(s, off, 64);
  if (g == 0) xsq[m] = s;
}

// codebook: csq + maxcs + bf16 convert, one read of cb
__global__ void vq_cbprep(const float* __restrict__ cb, float* __restrict__ csq,
                          int* __restrict__ maxcs, ushort_t* __restrict__ cbh) {
  int t = threadIdx.x;
  int k = blockIdx.x * 16 + (t >> 4);              // 512 blocks
  int g = t & 15;
  const float* row = cb + (size_t)k * C_;
  float s = 0.0f;
#pragma unroll
  for (int j = 0; j < 4; ++j) {
    float4 v = *(const float4*)&row[g * 4 + j * 64];
    s += v.x * v.x + v.y * v.y + v.z * v.z + v.w * v.w;
    ushort4 h;
    h.x = f2bf(v.x); h.y = f2bf(v.y); h.z = f2bf(v.z); h.w = f2bf(v.w);
    *(ushort4*)&cbh[(size_t)k * C_ + g * 4 + j * 64] = h;
  }
#pragma unroll
  for (int off = 1; off < 16; off <<= 1) s += __shfl_xor(s, off, 64);
  if (g == 0) {
    csq[k] = s;
    atomicMax(maxcs, __float_as_int(s));   // positive floats: int cmp == float cmp
  }
}

// ---------------- single-pass MFMA GEMM, A in registers ----------------
// 512 thr = 8 waves. Block: 256-row strip x 2048 codes (ns split of 4).
// Wave w owns rows r0 = strip*256 + w*32 .. +31, A (32 x 256) in 64 VGPR.
// B: 16 tiles of 128 codes x K=256, double-buffered LDS 2x64KB, XOR-swizzled
// (linear LDS dest + inverse-swizzled global source + swizzled ds_read).
// Output: lmax[m][256] fp16 = per-(row, 32-code-block) max of (csq - 2*dot).

#define STAGE(buf, t_)                                                        \
  {                                                                           \
    _Pragma("unroll")                                                         \
    for (int q = 0; q < 8; ++q) {                                             \
      int codeT = (w * 8 + q) * 2 + (l >> 5);                                 \
      int chunk = l & 31;                                                     \
      gld16(&Bs[(buf)][(w * 8 + q) * 512],                                    \
            &cbh[(size_t)(n0 + (t_) * 128 + codeT) * 256 +                    \
                 ((chunk ^ (codeT & 7)) * 8)]);                               \
    }                                                                         \
  }

__global__ void __launch_bounds__(512, 2)
vq_gemm(const ushort_t* __restrict__ xth, const ushort_t* __restrict__ cbh,
        const float* __restrict__ csq, __half* __restrict__ lmax) {
  __shared__ short Bs[2][128 * 256];   // 2 x 64 KB

  const int tid = threadIdx.x;
  const int w = tid >> 6, l = tid & 63;
  const int lr = l & 15, lk = l >> 4;
  const int strip = blockIdx.x >> 2, ns = blockIdx.x & 3;
  const int r0 = strip * 256 + w * 32;
  const int n0 = ns * 2048;

  // A fragments: a[i][ks] = row (r0+i*16+lr), k = ks*32 + lk*8 .. +8
  s8v a[2][8];
#pragma unroll
  for (int i = 0; i < 2; ++i)
#pragma unroll
    for (int ks = 0; ks < 8; ++ks)
      a[i][ks] = *(const s8v*)&xth[(size_t)(r0 + i * 16 + lr) * 256 + ks * 32 + lk * 8];

  STAGE(0, 0);
  __syncthreads();

  for (int t = 0; t < 16; ++t) {
    const int buf = t & 1;
    if (t < 15) STAGE(buf ^ 1, t + 1);   // issue next-tile loads BEFORE compute

    f4v acc[2][8];
#pragma unroll
    for (int i = 0; i < 2; ++i)
#pragma unroll
      for (int j = 0; j < 8; ++j) acc[i][j] = (f4v){0.f, 0.f, 0.f, 0.f};

#pragma unroll
    for (int ks = 0; ks < 8; ++ks) {
      s8v b[8];
#pragma unroll
      for (int j = 0; j < 8; ++j) {
        int jrow = j * 16 + lr;
        b[j] = *(const s8v*)&Bs[buf][jrow * 256 + (((ks * 4 + lk) ^ (lr & 7)) * 8)];
      }
#pragma unroll
      for (int i = 0; i < 2; ++i)
#pragma unroll
        for (int j = 0; j < 8; ++j)
          acc[i][j] = __builtin_amdgcn_mfma_f32_16x16x32_bf16(a[i][ks], b[j], acc[i][j], 0, 0, 0);
    }

    // epilogue: v = csq - 2*dot; max over 32-code blocks (j pair x 16 lr)
    float cq[8];
#pragma unroll
    for (int j = 0; j < 8; ++j) cq[j] = csq[n0 + t * 128 + j * 16 + lr];
#pragma unroll
    for (int i = 0; i < 2; ++i)
#pragma unroll
      for (int r = 0; r < 4; ++r) {
        float vb[4];
#pragma unroll
        for (int b2 = 0; b2 < 4; ++b2) {
          float v0 = __fmaf_rn(-2.0f, acc[i][2 * b2][r], cq[2 * b2]);
          float v1 = __fmaf_rn(-2.0f, acc[i][2 * b2 + 1][r], cq[2 * b2 + 1]);
          vb[b2] = fmaxf(v0, v1);
        }
#pragma unroll
        for (int off = 1; off < 16; off <<= 1)
#pragma unroll
          for (int b2 = 0; b2 < 4; ++b2)
            vb[b2] = fmaxf(vb[b2], __shfl_xor(vb[b2], off, 64));
        if (lr == 0) {
          short4 sv;
          sv.x = (short)__half_as_ushort(__float2half(vb[0]));
          sv.y = (short)__half_as_ushort(__float2half(vb[1]));
          sv.z = (short)__half_as_ushort(__float2half(vb[2]));
          sv.w = (short)__half_as_ushort(__float2half(vb[3]));
          *(short4*)&lmax[(size_t)(r0 + i * 16 + lk * 4 + r) * 256 + ns * 64 + t * 4] = sv;
        }
      }
    __syncthreads();   // all reads of Bs[buf] done; STAGE(t+1) drained (vmcnt 0 at barrier)
  }
}

// per-row threshold + candidate (row, 32-block) list
__global__ void __launch_bounds__(256)
vq_thr(const __half* __restrict__ lmax, const float* __restrict__ xsq,
       const int* __restrict__ maxcs, u32* __restrict__ list, u32* __restrict__ cnt) {
  __shared__ float wm[4];
  int m = blockIdx.x, t = threadIdx.x;
  float v = __half2float(lmax[(size_t)m * 256 + t]);
  float g = v;
#pragma unroll
  for (int off = 1; off < 64; off <<= 1) g = fmaxf(g, __shfl_xor(g, off, 64));
  if ((t & 63) == 0) wm[t >> 6] = g;
  __syncthreads();
  g = fmaxf(fmaxf(wm[0], wm[1]), fmaxf(wm[2], wm[3]));
  // rigorous: per-code |Delta d2'| <= 2*(2^-8+2^-16+2^-18)*sqrt(xsq*csq) ~ 0.0079*sqrt;
  // x2 for both sides of the comparison, + fp16 storage slack (0.25 x2). 2x headroom.
  float marg = 0.033f * sqrtf(xsq[m] * __int_as_float(*maxcs)) + 0.6f;
  if (v >= g - marg) {
    u32 idx = atomicAdd(cnt, 1u);
    if (idx < LIST_CAP) list[idx] = ((u32)m << 8) | (u32)t;
  }
}

// exact fp32 rescore of qualifying 32-code blocks; one wave per entry.
// CRITICAL: mirrors numpy op order incl. sqrt — sqrt collapses near-ties and
// numpy's argmax then picks the smaller index; key packs (dist_bits, ~k).
__global__ void __launch_bounds__(256)
vq_rescore(const u32* __restrict__ list, const u32* __restrict__ cnt,
           const float* __restrict__ xtf, const float* __restrict__ cb,
           const float* __restrict__ xsq, const float* __restrict__ csq,
           u64* __restrict__ keys) {
  u32 n = *cnt; if (n > LIST_CAP) n = LIST_CAP;
  int wid = (blockIdx.x * 256 + threadIdx.x) >> 6;
  int l = threadIdx.x & 63;
  int nw = (gridDim.x * 256) >> 6;
  for (u32 e = wid; e < n; e += nw) {
    u32 ent = list[e];
    int m = (int)(ent >> 8), blk = (int)(ent & 255u);
    float4 xv = *(const float4*)&xtf[(size_t)m * C_ + l * 4];
    float xq = xsq[m];
    float best = -1.0f; int bestk = 0;
#pragma unroll 4
    for (int c = 0; c < 32; ++c) {
      int k = blk * 32 + c;
      float4 cv = *(const float4*)&cb[(size_t)k * C_ + l * 4];
      float p = xv.x * cv.x + xv.y * cv.y + xv.z * cv.z + xv.w * cv.w;
#pragma unroll
      for (int off = 1; off < 64; off <<= 1) p += __shfl_xor(p, off, 64);
      // exact reference op order: (x_sq + c_sq) - 2*dot, clamp, sqrt
      float d2 = __fsub_rn(__fadd_rn(xq, csq[k]), __fmul_rn(2.0f, p));
      float dist = sqrtf(fmaxf(d2, 0.0f));
      if (dist > best) { best = dist; bestk = k; }   // strict: first (smaller k) wins tie
    }
    if (l == 0) {
      u64 key = ((u64)__float_as_uint(best) << 32) |
                (u64)(0xFFFFFFFFu - (u32)bestk);
      atomicMax(&keys[m], key);
    }
  }
}

// ---------------- outputs ----------------

__global__ void vq_code(const u64* __restrict__ keys, float* __restrict__ out) {
  int m = blockIdx.x * 256 + threadIdx.x;
  u32 k = 0xFFFFFFFFu - (u32)(keys[m] & 0xFFFFFFFFull);
  out[m] = (float)k;
}

__global__ void __launch_bounds__(256)
vq_gather(const u64* __restrict__ keys, const float* __restrict__ cb,
          const float* __restrict__ x, float* __restrict__ emb,
          float* __restrict__ loss_acc) {
  __shared__ float rows[32 * 260];
  __shared__ int codes_s[32];
  __shared__ float partial[4];
  int t = threadIdx.x;
  int b = blockIdx.x >> 6;
  int l0 = (blockIdx.x & 63) * 32;
  if (t < 32) {
    u64 key = keys[b * L_ + l0 + t];
    codes_s[t] = (int)(0xFFFFFFFFu - (u32)(key & 0xFFFFFFFFull));
  }
  __syncthreads();
  {
    int r = t >> 3, c4 = t & 7;
    const float* src = cb + (size_t)codes_s[r] * C_;
#pragma unroll
    for (int j = 0; j < 8; ++j) {
      float4 v = *(const float4*)&src[(c4 + 8 * j) * 4];
      *(float4*)&rows[r * 260 + (c4 + 8 * j) * 4] = v;
    }
  }
  __syncthreads();
  float ls = 0.0f;
  int l = t & 31, cg = t >> 5;
#pragma unroll 4
  for (int cs = 0; cs < 32; ++cs) {
    int c = cg * 32 + cs;
    float v = rows[l * 260 + c];
    size_t gi = (size_t)(b * C_ + c) * L_ + l0 + l;
    emb[gi] = v;
    float d = x[gi] - v;
    ls = fmaf(d, d, ls);
  }
#pragma unroll
  for (int off = 1; off < 64; off <<= 1) ls += __shfl_xor(ls, off, 64);
  if ((t & 63) == 0) partial[t >> 6] = ls;
  __syncthreads();
  if (t == 0)
    atomicAdd(loss_acc, partial[0] + partial[1] + partial[2] + partial[3]);
}

__global__ void vq_loss(const float* __restrict__ loss_acc, float* __restrict__ out) {
  out[0] = loss_acc[0] / 4194304.0f;
}

extern "C" void kernel_launch(void* const* d_in, const int* in_sizes, int n_in,
                              void* d_out, int out_size, void* d_ws, size_t ws_size,
                              hipStream_t stream) {
  const float* x  = (const float*)d_in[0];   // (8, 256, 2048)
  const float* cb = (const float*)d_in[1];   // (8192, 256)
  float* out = (float*)d_out;                // [code(16384) | emb(4194304) | loss(1)]
  char* ws = (char*)d_ws;

  u64* keys      = (u64*)(ws + WS_KEYS);
  u32* cnt       = (u32*)(ws + WS_CNT);
  int* maxcs     = (int*)(ws + WS_MAXCS);
  float* loss_a  = (float*)(ws + WS_LOSS);
  float* xsq     = (float*)(ws + WS_XSQ);
  float* csq     = (float*)(ws + WS_CSQ);
  u32* list      = (u32*)(ws + WS_LIST);
  __half* lmax   = (__half*)(ws + WS_LMAX);
  ushort_t* xth  = (ushort_t*)(ws + WS_XTH);
  ushort_t* cbh  = (ushort_t*)(ws + WS_CBH);
  float* xtf     = out + M_;                 // emb region doubles as fp32 x^T scratch

  hipMemsetAsync(ws, 0, 131084, stream);     // keys + cnt + maxcs + loss

  vq_transpose<<<1024, 256, 0, stream>>>(x, xtf, xth);
  vq_cbprep<<<K_ / 16, 256, 0, stream>>>(cb, csq, maxcs, cbh);
  vq_xsqt<<<M_ / 16, 256, 0, stream>>>(xtf, xsq);
  vq_gemm<<<256, 512, 0, stream>>>(xth, cbh, csq, lmax);
  vq_thr<<<M_, 256, 0, stream>>>(lmax, xsq, maxcs, list, cnt);
  vq_rescore<<<512, 256, 0, stream>>>(list, cnt, xtf, cb, xsq, csq, keys);
  vq_code<<<M_ / 256, 256, 0, stream>>>(keys, out);
  vq_gather<<<(B_ * L_) / 32, 256, 0, stream>>>(keys, cb, x, out + M_, loss_a);
  vq_loss<<<1, 1, 0, stream>>>(loss_a, out + M_ + (size_t)B_ * C_ * L_);
}

// Round 5
// 307.864 us; speedup vs baseline: 2.0579x; 2.0579x over previous
//
#include <hip/hip_runtime.h>
#include <hip/hip_fp16.h>
#include <stdint.h>

typedef unsigned int u32;
typedef unsigned long long u64;
typedef unsigned short ushort_t;

// Problem constants
#define B_ 8
#define C_ 256
#define L_ 2048
#define K_ 8192
#define M_ 16384   // B_*L_

// ---- workspace layout (bytes) ----  (WS_NEED = 25460992, proven to fit)
#define WS_KEYS   0            // u64[16384] -> 131072
#define WS_CNT    131072       // u32
#define WS_MAXCS  131076       // u32 (float bits, positive -> int cmp ok)
#define WS_LOSS   131080       // f32
#define WS_XSQ    131328       // f32[16384] -> 196864
#define WS_CSQ    196864       // f32[8192]  -> 229632
#define WS_LIST   295168       // u32[1M]    -> 4489472
#define WS_LMAX   4489472      // fp16[16384*256] -> 12878080
#define WS_XTH    12878080     // bf16[16384*256] -> 21266688
#define WS_CBH    21266688     // bf16[8192*256]  -> 25460992
#define LIST_CAP  1048576u

typedef __attribute__((ext_vector_type(8))) short s8v;   // 8 x bf16 (4 VGPR)
typedef __attribute__((ext_vector_type(4))) float f4v;

__device__ __forceinline__ ushort_t f2bf(float f) {
  u32 u = __float_as_uint(f);
  u32 r = (u + 0x7FFFu + ((u >> 16) & 1u)) >> 16;   // RN-even
  return (ushort_t)r;
}

__device__ __forceinline__ void gld16(void* lds, const void* g) {
  __builtin_amdgcn_global_load_lds(
      (const __attribute__((address_space(1))) u32*)g,
      (__attribute__((address_space(3))) u32*)lds, 16, 0, 0);
}

// ---------------- prep kernels ----------------

// transpose x (B,C,L) -> xt fp32 (M,C) [into emb out region] + bf16 (M,C) [ws]
__global__ void __launch_bounds__(256)
vq_transpose(const float* __restrict__ x, float* __restrict__ xtf,
             ushort_t* __restrict__ xth) {
  __shared__ float t[64][65];
  int tid = threadIdx.x;
  int b  = blockIdx.x >> 7;
  int cc = (blockIdx.x >> 5) & 3;
  int lc = blockIdx.x & 31;
#pragma unroll
  for (int j = 0; j < 4; ++j) {
    int c  = (tid >> 4) + j * 16;
    int lq = tid & 15;
    float4 v = *(const float4*)&x[((size_t)(b * C_ + cc * 64 + c)) * L_ + lc * 64 + lq * 4];
    t[c][lq * 4 + 0] = v.x; t[c][lq * 4 + 1] = v.y;
    t[c][lq * 4 + 2] = v.z; t[c][lq * 4 + 3] = v.w;
  }
  __syncthreads();
  int l = tid >> 2, qc = tid & 3;
  size_t m = (size_t)b * L_ + lc * 64 + l;
#pragma unroll
  for (int j = 0; j < 4; ++j) {
    int q = qc + j * 4;                    // float4 index 0..15
    float4 v = make_float4(t[q * 4 + 0][l], t[q * 4 + 1][l],
                           t[q * 4 + 2][l], t[q * 4 + 3][l]);
    *(float4*)&xtf[m * C_ + cc * 64 + q * 4] = v;
    ushort4 h;
    h.x = f2bf(v.x); h.y = f2bf(v.y); h.z = f2bf(v.z); h.w = f2bf(v.w);
    *(ushort4*)&xth[m * C_ + cc * 64 + q * 4] = h;
  }
}

// xsq from transposed fp32 rows (coalesced, deterministic order)
__global__ void vq_xsqt(const float* __restrict__ xtf, float* __restrict__ xsq) {
  int t = threadIdx.x;
  int m = blockIdx.x * 16 + (t >> 4);              // 1024 blocks
  int g = t & 15;
  const float* row = xtf + (size_t)m * C_;
  float s = 0.0f;
#pragma unroll
  for (int j = 0; j < 4; ++j) {
    float4 v = *(const float4*)&row[g * 4 + j * 64];
    s += v.x * v.x + v.y * v.y + v.z * v.z + v.w * v.w;
  }
#pragma unroll
  for (int off = 1; off < 16; off <<= 1) s += __shfl_xor(s, off, 64);
  if (g == 0) xsq[m] = s;
}

// codebook: csq + maxcs + bf16 convert, one read of cb
__global__ void vq_cbprep(const float* __restrict__ cb, float* __restrict__ csq,
                          int* __restrict__ maxcs, ushort_t* __restrict__ cbh) {
  int t = threadIdx.x;
  int k = blockIdx.x * 16 + (t >> 4);              // 512 blocks
  int g = t & 15;
  const float* row = cb + (size_t)k * C_;
  float s = 0.0f;
#pragma unroll
  for (int j = 0; j < 4; ++j) {
    float4 v = *(const float4*)&row[g * 4 + j * 64];
    s += v.x * v.x + v.y * v.y + v.z * v.z + v.w * v.w;
    ushort4 h;
    h.x = f2bf(v.x); h.y = f2bf(v.y); h.z = f2bf(v.z); h.w = f2bf(v.w);
    *(ushort4*)&cbh[(size_t)k * C_ + g * 4 + j * 64] = h;
  }
#pragma unroll
  for (int off = 1; off < 16; off <<= 1) s += __shfl_xor(s, off, 64);
  if (g == 0) {
    csq[k] = s;
    atomicMax(maxcs, __float_as_int(s));   // positive floats: int cmp == float cmp
  }
}

// ---------------- single-pass MFMA GEMM, A in registers ----------------
// 512 thr = 8 waves. Block: 256-row strip x 2048 codes (ns split of 4).
// Wave w owns rows r0 = strip*256 + w*32 .. +31, A (32 x 256) in 64 VGPR.
// B: 16 tiles of 128 codes x K=256, double-buffered LDS 2x64KB, XOR-swizzled
// (linear LDS dest + inverse-swizzled global source + swizzled ds_read).
// Output: lmax[m][256] fp16 = per-(row, 32-code-block) max of (csq - 2*dot).

#define STAGE(buf, t_)                                                        \
  {                                                                           \
    _Pragma("unroll")                                                         \
    for (int q = 0; q < 8; ++q) {                                             \
      int codeT = (w * 8 + q) * 2 + (l >> 5);                                 \
      int chunk = l & 31;                                                     \
      gld16(&Bs[(buf)][(w * 8 + q) * 512],                                    \
            &cbh[(size_t)(n0 + (t_) * 128 + codeT) * 256 +                    \
                 ((chunk ^ (codeT & 7)) * 8)]);                               \
    }                                                                         \
  }

__global__ void __launch_bounds__(512, 2)
vq_gemm(const ushort_t* __restrict__ xth, const ushort_t* __restrict__ cbh,
        const float* __restrict__ csq, __half* __restrict__ lmax) {
  __shared__ short Bs[2][128 * 256];   // 2 x 64 KB

  const int tid = threadIdx.x;
  const int w = tid >> 6, l = tid & 63;
  const int lr = l & 15, lk = l >> 4;
  const int strip = blockIdx.x >> 2, ns = blockIdx.x & 3;
  const int r0 = strip * 256 + w * 32;
  const int n0 = ns * 2048;

  // A fragments: a[i][ks] = row (r0+i*16+lr), k = ks*32 + lk*8 .. +8
  s8v a[2][8];
#pragma unroll
  for (int i = 0; i < 2; ++i)
#pragma unroll
    for (int ks = 0; ks < 8; ++ks)
      a[i][ks] = *(const s8v*)&xth[(size_t)(r0 + i * 16 + lr) * 256 + ks * 32 + lk * 8];

  STAGE(0, 0);
  __syncthreads();

  for (int t = 0; t < 16; ++t) {
    const int buf = t & 1;
    if (t < 15) STAGE(buf ^ 1, t + 1);   // issue next-tile loads BEFORE compute

    f4v acc[2][8];
#pragma unroll
    for (int i = 0; i < 2; ++i)
#pragma unroll
      for (int j = 0; j < 8; ++j) acc[i][j] = (f4v){0.f, 0.f, 0.f, 0.f};

#pragma unroll
    for (int ks = 0; ks < 8; ++ks) {
      s8v b[8];
#pragma unroll
      for (int j = 0; j < 8; ++j) {
        int jrow = j * 16 + lr;
        b[j] = *(const s8v*)&Bs[buf][jrow * 256 + (((ks * 4 + lk) ^ (lr & 7)) * 8)];
      }
#pragma unroll
      for (int i = 0; i < 2; ++i)
#pragma unroll
        for (int j = 0; j < 8; ++j)
          acc[i][j] = __builtin_amdgcn_mfma_f32_16x16x32_bf16(a[i][ks], b[j], acc[i][j], 0, 0, 0);
    }

    // epilogue: v = csq - 2*dot; max over 32-code blocks (j pair x 16 lr)
    float cq[8];
#pragma unroll
    for (int j = 0; j < 8; ++j) cq[j] = csq[n0 + t * 128 + j * 16 + lr];
#pragma unroll
    for (int i = 0; i < 2; ++i)
#pragma unroll
      for (int r = 0; r < 4; ++r) {
        float vb[4];
#pragma unroll
        for (int b2 = 0; b2 < 4; ++b2) {
          float v0 = __fmaf_rn(-2.0f, acc[i][2 * b2][r], cq[2 * b2]);
          float v1 = __fmaf_rn(-2.0f, acc[i][2 * b2 + 1][r], cq[2 * b2 + 1]);
          vb[b2] = fmaxf(v0, v1);
        }
#pragma unroll
        for (int off = 1; off < 16; off <<= 1)
#pragma unroll
          for (int b2 = 0; b2 < 4; ++b2)
            vb[b2] = fmaxf(vb[b2], __shfl_xor(vb[b2], off, 64));
        if (lr == 0) {
          short4 sv;
          sv.x = (short)__half_as_ushort(__float2half(vb[0]));
          sv.y = (short)__half_as_ushort(__float2half(vb[1]));
          sv.z = (short)__half_as_ushort(__float2half(vb[2]));
          sv.w = (short)__half_as_ushort(__float2half(vb[3]));
          *(short4*)&lmax[(size_t)(r0 + i * 16 + lk * 4 + r) * 256 + ns * 64 + t * 4] = sv;
        }
      }
    __syncthreads();   // all reads of Bs[buf] done; STAGE(t+1) drained (vmcnt 0 at barrier)
  }
}

// per-row threshold + candidate list, block-aggregated (ONE global atomic per
// block — round 4's ~50K same-address atomicAdds were 334 us of serialization).
// 256 blocks x 256 thr; wave = one row per iteration (16 rows/wave, 64 rows/block).
__global__ void __launch_bounds__(256)
vq_thr(const __half* __restrict__ lmax, const float* __restrict__ xsq,
       const int* __restrict__ maxcs, u32* __restrict__ list, u32* __restrict__ cnt) {
  __shared__ u32 wcnt[4];
  __shared__ u32 gbase_s;
  const int t = threadIdx.x, w = t >> 6, l = t & 63;
  const int m0 = blockIdx.x * 64 + w * 16;
  const float mc = __int_as_float(*maxcs);

  ushort4 hv[16];
  float thv[16];
  u32 wtot = 0;
  // pass 1: load row, wave-max, threshold, count qualifiers
#pragma unroll
  for (int i = 0; i < 16; ++i) {
    int m = m0 + i;
    hv[i] = *(const ushort4*)&lmax[(size_t)m * 256 + l * 4];
    float v0 = __half2float(__ushort_as_half(hv[i].x));
    float v1 = __half2float(__ushort_as_half(hv[i].y));
    float v2 = __half2float(__ushort_as_half(hv[i].z));
    float v3 = __half2float(__ushort_as_half(hv[i].w));
    float g = fmaxf(fmaxf(v0, v1), fmaxf(v2, v3));
#pragma unroll
    for (int off = 1; off < 64; off <<= 1) g = fmaxf(g, __shfl_xor(g, off, 64));
    // rigorous margin: 2*(bf16 dot err + fp16 storage slack), ~2x headroom
    float th = g - (0.033f * sqrtf(xsq[m] * mc) + 0.6f);
    thv[i] = th;
    wtot += __popcll(__ballot(v0 >= th));
    wtot += __popcll(__ballot(v1 >= th));
    wtot += __popcll(__ballot(v2 >= th));
    wtot += __popcll(__ballot(v3 >= th));
  }
  if (l == 0) wcnt[w] = wtot;
  __syncthreads();
  if (t == 0) gbase_s = atomicAdd(cnt, wcnt[0] + wcnt[1] + wcnt[2] + wcnt[3]);
  __syncthreads();
  u32 off = gbase_s;
  for (int ww = 0; ww < w; ++ww) off += wcnt[ww];
  // pass 2: write entries at deterministic ballot-prefix positions
#pragma unroll
  for (int i = 0; i < 16; ++i) {
    int m = m0 + i;
    float th = thv[i];
    float v[4];
    v[0] = __half2float(__ushort_as_half(hv[i].x));
    v[1] = __half2float(__ushort_as_half(hv[i].y));
    v[2] = __half2float(__ushort_as_half(hv[i].z));
    v[3] = __half2float(__ushort_as_half(hv[i].w));
#pragma unroll
    for (int j = 0; j < 4; ++j) {
      u64 mask = __ballot(v[j] >= th);
      if (v[j] >= th) {
        u32 pos = off + (u32)__popcll(mask & ((1ull << l) - 1ull));
        if (pos < LIST_CAP) list[pos] = ((u32)m << 8) | (u32)(l * 4 + j);
      }
      off += (u32)__popcll(mask);
    }
  }
}

// exact fp32 rescore of qualifying 32-code blocks; one wave per entry.
// Mirrors numpy op order incl. sqrt — sqrt collapses near-ties and numpy's
// argmax then picks the smaller index; key packs (dist_bits, ~k).
__global__ void __launch_bounds__(256)
vq_rescore(const u32* __restrict__ list, const u32* __restrict__ cnt,
           const float* __restrict__ xtf, const float* __restrict__ cb,
           const float* __restrict__ xsq, const float* __restrict__ csq,
           u64* __restrict__ keys) {
  u32 n = *cnt; if (n > LIST_CAP) n = LIST_CAP;
  int wid = (blockIdx.x * 256 + threadIdx.x) >> 6;
  int l = threadIdx.x & 63;
  int nw = (gridDim.x * 256) >> 6;
  for (u32 e = wid; e < n; e += nw) {
    u32 ent = list[e];
    int m = (int)(ent >> 8), blk = (int)(ent & 255u);
    float4 xv = *(const float4*)&xtf[(size_t)m * C_ + l * 4];
    float xq = xsq[m];
    float best = -1.0f; int bestk = 0;
#pragma unroll 4
    for (int c = 0; c < 32; ++c) {
      int k = blk * 32 + c;
      float4 cv = *(const float4*)&cb[(size_t)k * C_ + l * 4];
      float p = xv.x * cv.x + xv.y * cv.y + xv.z * cv.z + xv.w * cv.w;
#pragma unroll
      for (int off = 1; off < 64; off <<= 1) p += __shfl_xor(p, off, 64);
      // exact reference op order: (x_sq + c_sq) - 2*dot, clamp, sqrt
      float d2 = __fsub_rn(__fadd_rn(xq, csq[k]), __fmul_rn(2.0f, p));
      float dist = sqrtf(fmaxf(d2, 0.0f));
      if (dist > best) { best = dist; bestk = k; }   // strict: first (smaller k) wins tie
    }
    if (l == 0) {
      u64 key = ((u64)__float_as_uint(best) << 32) |
                (u64)(0xFFFFFFFFu - (u32)bestk);
      atomicMax(&keys[m], key);
    }
  }
}

// ---------------- outputs ----------------

__global__ void vq_code(const u64* __restrict__ keys, float* __restrict__ out) {
  int m = blockIdx.x * 256 + threadIdx.x;
  u32 k = 0xFFFFFFFFu - (u32)(keys[m] & 0xFFFFFFFFull);
  out[m] = (float)k;
}

__global__ void __launch_bounds__(256)
vq_gather(const u64* __restrict__ keys, const float* __restrict__ cb,
          const float* __restrict__ x, float* __restrict__ emb,
          float* __restrict__ loss_acc) {
  __shared__ float rows[32 * 260];
  __shared__ int codes_s[32];
  __shared__ float partial[4];
  int t = threadIdx.x;
  int b = blockIdx.x >> 6;
  int l0 = (blockIdx.x & 63) * 32;
  if (t < 32) {
    u64 key = keys[b * L_ + l0 + t];
    codes_s[t] = (int)(0xFFFFFFFFu - (u32)(key & 0xFFFFFFFFull));
  }
  __syncthreads();
  {
    int r = t >> 3, c4 = t & 7;
    const float* src = cb + (size_t)codes_s[r] * C_;
#pragma unroll
    for (int j = 0; j < 8; ++j) {
      float4 v = *(const float4*)&src[(c4 + 8 * j) * 4];
      *(float4*)&rows[r * 260 + (c4 + 8 * j) * 4] = v;
    }
  }
  __syncthreads();
  float ls = 0.0f;
  int l = t & 31, cg = t >> 5;
#pragma unroll 4
  for (int cs = 0; cs < 32; ++cs) {
    int c = cg * 32 + cs;
    float v = rows[l * 260 + c];
    size_t gi = (size_t)(b * C_ + c) * L_ + l0 + l;
    emb[gi] = v;
    float d = x[gi] - v;
    ls = fmaf(d, d, ls);
  }
#pragma unroll
  for (int off = 1; off < 64; off <<= 1) ls += __shfl_xor(ls, off, 64);
  if ((t & 63) == 0) partial[t >> 6] = ls;
  __syncthreads();
  if (t == 0)
    atomicAdd(loss_acc, partial[0] + partial[1] + partial[2] + partial[3]);
}

__global__ void vq_loss(const float* __restrict__ loss_acc, float* __restrict__ out) {
  out[0] = loss_acc[0] / 4194304.0f;
}

extern "C" void kernel_launch(void* const* d_in, const int* in_sizes, int n_in,
                              void* d_out, int out_size, void* d_ws, size_t ws_size,
                              hipStream_t stream) {
  const float* x  = (const float*)d_in[0];   // (8, 256, 2048)
  const float* cb = (const float*)d_in[1];   // (8192, 256)
  float* out = (float*)d_out;                // [code(16384) | emb(4194304) | loss(1)]
  char* ws = (char*)d_ws;

  u64* keys      = (u64*)(ws + WS_KEYS);
  u32* cnt       = (u32*)(ws + WS_CNT);
  int* maxcs     = (int*)(ws + WS_MAXCS);
  float* loss_a  = (float*)(ws + WS_LOSS);
  float* xsq     = (float*)(ws + WS_XSQ);
  float* csq     = (float*)(ws + WS_CSQ);
  u32* list      = (u32*)(ws + WS_LIST);
  __half* lmax   = (__half*)(ws + WS_LMAX);
  ushort_t* xth  = (ushort_t*)(ws + WS_XTH);
  ushort_t* cbh  = (ushort_t*)(ws + WS_CBH);
  float* xtf     = out + M_;                 // emb region doubles as fp32 x^T scratch

  hipMemsetAsync(ws, 0, 131084, stream);     // keys + cnt + maxcs + loss

  vq_transpose<<<1024, 256, 0, stream>>>(x, xtf, xth);
  vq_cbprep<<<K_ / 16, 256, 0, stream>>>(cb, csq, maxcs, cbh);
  vq_xsqt<<<M_ / 16, 256, 0, stream>>>(xtf, xsq);
  vq_gemm<<<256, 512, 0, stream>>>(xth, cbh, csq, lmax);
  vq_thr<<<256, 256, 0, stream>>>(lmax, xsq, maxcs, list, cnt);
  vq_rescore<<<512, 256, 0, stream>>>(list, cnt, xtf, cb, xsq, csq, keys);
  vq_code<<<M_ / 256, 256, 0, stream>>>(keys, out);
  vq_gather<<<(B_ * L_) / 32, 256, 0, stream>>>(keys, cb, x, out + M_, loss_a);
  vq_loss<<<1, 1, 0, stream>>>(loss_a, out + M_ + (size_t)B_ * C_ * L_);
}

// Round 6
// 235.068 us; speedup vs baseline: 2.6952x; 1.3097x over previous
//
#include <hip/hip_runtime.h>
#include <hip/hip_fp16.h>
#include <stdint.h>

typedef unsigned int u32;
typedef unsigned long long u64;
typedef unsigned short ushort_t;

// Problem constants
#define B_ 8
#define C_ 256
#define L_ 2048
#define K_ 8192
#define M_ 16384   // B_*L_

// ---- workspace layout (bytes) ----  (WS_NEED = 25460992, proven to fit)
#define WS_KEYS   0            // u64[16384] -> 131072
#define WS_CNT    131072       // u32
#define WS_MAXCS  131076       // u32 (float bits, positive -> int cmp ok)
#define WS_LOSS   131080       // f32
#define WS_XSQ    131328       // f32[16384] -> 196864
#define WS_CSQ    196864       // f32[8192]  -> 229632
#define WS_LIST   295168       // u32[1M]    -> 4489472
#define WS_LMAX   4489472      // fp16[16384*256] -> 12878080
#define WS_XTH    12878080     // bf16[16384*256] -> 21266688
#define WS_CBH    21266688     // bf16[8192*256]  -> 25460992
#define LIST_CAP  1048576u

typedef __attribute__((ext_vector_type(8))) short s8v;   // 8 x bf16 (4 VGPR)
typedef __attribute__((ext_vector_type(4))) float f4v;

__device__ __forceinline__ ushort_t f2bf(float f) {
  u32 u = __float_as_uint(f);
  u32 r = (u + 0x7FFFu + ((u >> 16) & 1u)) >> 16;   // RN-even
  return (ushort_t)r;
}

__device__ __forceinline__ void gld16(void* lds, const void* g) {
  __builtin_amdgcn_global_load_lds(
      (const __attribute__((address_space(1))) u32*)g,
      (__attribute__((address_space(3))) u32*)lds, 16, 0, 0);
}

// ---------------- prep kernels ----------------

// transpose x (B,C,L) -> xt fp32 (M,C) [into emb out region] + bf16 (M,C) [ws]
__global__ void __launch_bounds__(256)
vq_transpose(const float* __restrict__ x, float* __restrict__ xtf,
             ushort_t* __restrict__ xth) {
  __shared__ float t[64][65];
  int tid = threadIdx.x;
  int b  = blockIdx.x >> 7;
  int cc = (blockIdx.x >> 5) & 3;
  int lc = blockIdx.x & 31;
#pragma unroll
  for (int j = 0; j < 4; ++j) {
    int c  = (tid >> 4) + j * 16;
    int lq = tid & 15;
    float4 v = *(const float4*)&x[((size_t)(b * C_ + cc * 64 + c)) * L_ + lc * 64 + lq * 4];
    t[c][lq * 4 + 0] = v.x; t[c][lq * 4 + 1] = v.y;
    t[c][lq * 4 + 2] = v.z; t[c][lq * 4 + 3] = v.w;
  }
  __syncthreads();
  int l = tid >> 2, qc = tid & 3;
  size_t m = (size_t)b * L_ + lc * 64 + l;
#pragma unroll
  for (int j = 0; j < 4; ++j) {
    int q = qc + j * 4;                    // float4 index 0..15
    float4 v = make_float4(t[q * 4 + 0][l], t[q * 4 + 1][l],
                           t[q * 4 + 2][l], t[q * 4 + 3][l]);
    *(float4*)&xtf[m * C_ + cc * 64 + q * 4] = v;
    ushort4 h;
    h.x = f2bf(v.x); h.y = f2bf(v.y); h.z = f2bf(v.z); h.w = f2bf(v.w);
    *(ushort4*)&xth[m * C_ + cc * 64 + q * 4] = h;
  }
}

// xsq from transposed fp32 rows (coalesced, deterministic order)
__global__ void vq_xsqt(const float* __restrict__ xtf, float* __restrict__ xsq) {
  int t = threadIdx.x;
  int m = blockIdx.x * 16 + (t >> 4);              // 1024 blocks
  int g = t & 15;
  const float* row = xtf + (size_t)m * C_;
  float s = 0.0f;
#pragma unroll
  for (int j = 0; j < 4; ++j) {
    float4 v = *(const float4*)&row[g * 4 + j * 64];
    s += v.x * v.x + v.y * v.y + v.z * v.z + v.w * v.w;
  }
#pragma unroll
  for (int off = 1; off < 16; off <<= 1) s += __shfl_xor(s, off, 64);
  if (g == 0) xsq[m] = s;
}

// codebook: csq + maxcs + bf16 convert, one read of cb
__global__ void vq_cbprep(const float* __restrict__ cb, float* __restrict__ csq,
                          int* __restrict__ maxcs, ushort_t* __restrict__ cbh) {
  int t = threadIdx.x;
  int k = blockIdx.x * 16 + (t >> 4);              // 512 blocks
  int g = t & 15;
  const float* row = cb + (size_t)k * C_;
  float s = 0.0f;
#pragma unroll
  for (int j = 0; j < 4; ++j) {
    float4 v = *(const float4*)&row[g * 4 + j * 64];
    s += v.x * v.x + v.y * v.y + v.z * v.z + v.w * v.w;
    ushort4 h;
    h.x = f2bf(v.x); h.y = f2bf(v.y); h.z = f2bf(v.z); h.w = f2bf(v.w);
    *(ushort4*)&cbh[(size_t)k * C_ + g * 4 + j * 64] = h;
  }
#pragma unroll
  for (int off = 1; off < 16; off <<= 1) s += __shfl_xor(s, off, 64);
  if (g == 0) {
    csq[k] = s;
    atomicMax(maxcs, __float_as_int(s));   // positive floats: int cmp == float cmp
  }
}

// ---------------- single-pass MFMA GEMM, A in registers ----------------
// 512 thr = 8 waves. Block: 256-row strip x 2048 codes (ns split of 4).
// Wave w owns rows r0 = strip*256 + w*32 .. +31, A (32 x 256) in 64 VGPR.
// B: 16 tiles of 128 codes x K=256, double-buffered LDS 2x64KB, XOR-swizzled
// (linear LDS dest + inverse-swizzled global source + swizzled ds_read).
// Output: lmax[m][256] fp16 = per-(row, 32-code-block) max of (csq - 2*dot).

#define STAGE(buf, t_)                                                        \
  {                                                                           \
    _Pragma("unroll")                                                         \
    for (int q = 0; q < 8; ++q) {                                             \
      int codeT = (w * 8 + q) * 2 + (l >> 5);                                 \
      int chunk = l & 31;                                                     \
      gld16(&Bs[(buf)][(w * 8 + q) * 512],                                    \
            &cbh[(size_t)(n0 + (t_) * 128 + codeT) * 256 +                    \
                 ((chunk ^ (codeT & 7)) * 8)]);                               \
    }                                                                         \
  }

__global__ void __launch_bounds__(512, 2)
vq_gemm(const ushort_t* __restrict__ xth, const ushort_t* __restrict__ cbh,
        const float* __restrict__ csq, __half* __restrict__ lmax) {
  __shared__ short Bs[2][128 * 256];   // 2 x 64 KB

  const int tid = threadIdx.x;
  const int w = tid >> 6, l = tid & 63;
  const int lr = l & 15, lk = l >> 4;
  const int strip = blockIdx.x >> 2, ns = blockIdx.x & 3;
  const int r0 = strip * 256 + w * 32;
  const int n0 = ns * 2048;

  // A fragments: a[i][ks] = row (r0+i*16+lr), k = ks*32 + lk*8 .. +8
  s8v a[2][8];
#pragma unroll
  for (int i = 0; i < 2; ++i)
#pragma unroll
    for (int ks = 0; ks < 8; ++ks)
      a[i][ks] = *(const s8v*)&xth[(size_t)(r0 + i * 16 + lr) * 256 + ks * 32 + lk * 8];

  STAGE(0, 0);
  __syncthreads();

  for (int t = 0; t < 16; ++t) {
    const int buf = t & 1;
    if (t < 15) STAGE(buf ^ 1, t + 1);   // issue next-tile loads BEFORE compute

    f4v acc[2][8];
#pragma unroll
    for (int i = 0; i < 2; ++i)
#pragma unroll
      for (int j = 0; j < 8; ++j) acc[i][j] = (f4v){0.f, 0.f, 0.f, 0.f};

#pragma unroll
    for (int ks = 0; ks < 8; ++ks) {
      s8v b[8];
#pragma unroll
      for (int j = 0; j < 8; ++j) {
        int jrow = j * 16 + lr;
        b[j] = *(const s8v*)&Bs[buf][jrow * 256 + (((ks * 4 + lk) ^ (lr & 7)) * 8)];
      }
#pragma unroll
      for (int i = 0; i < 2; ++i)
#pragma unroll
        for (int j = 0; j < 8; ++j)
          acc[i][j] = __builtin_amdgcn_mfma_f32_16x16x32_bf16(a[i][ks], b[j], acc[i][j], 0, 0, 0);
    }

    // epilogue: v = csq - 2*dot; max over 32-code blocks (j pair x 16 lr)
    float cq[8];
#pragma unroll
    for (int j = 0; j < 8; ++j) cq[j] = csq[n0 + t * 128 + j * 16 + lr];
#pragma unroll
    for (int i = 0; i < 2; ++i)
#pragma unroll
      for (int r = 0; r < 4; ++r) {
        float vb[4];
#pragma unroll
        for (int b2 = 0; b2 < 4; ++b2) {
          float v0 = __fmaf_rn(-2.0f, acc[i][2 * b2][r], cq[2 * b2]);
          float v1 = __fmaf_rn(-2.0f, acc[i][2 * b2 + 1][r], cq[2 * b2 + 1]);
          vb[b2] = fmaxf(v0, v1);
        }
#pragma unroll
        for (int off = 1; off < 16; off <<= 1)
#pragma unroll
          for (int b2 = 0; b2 < 4; ++b2)
            vb[b2] = fmaxf(vb[b2], __shfl_xor(vb[b2], off, 64));
        if (lr == 0) {
          short4 sv;
          sv.x = (short)__half_as_ushort(__float2half(vb[0]));
          sv.y = (short)__half_as_ushort(__float2half(vb[1]));
          sv.z = (short)__half_as_ushort(__float2half(vb[2]));
          sv.w = (short)__half_as_ushort(__float2half(vb[3]));
          *(short4*)&lmax[(size_t)(r0 + i * 16 + lk * 4 + r) * 256 + ns * 64 + t * 4] = sv;
        }
      }
    __syncthreads();   // all reads of Bs[buf] done; STAGE(t+1) drained (vmcnt 0 at barrier)
  }
}

// per-row threshold + candidate list, block-aggregated (one global atomic per
// block; entries at deterministic ballot-prefix positions).
__global__ void __launch_bounds__(256)
vq_thr(const __half* __restrict__ lmax, const float* __restrict__ xsq,
       const int* __restrict__ maxcs, u32* __restrict__ list, u32* __restrict__ cnt) {
  __shared__ u32 wcnt[4];
  __shared__ u32 gbase_s;
  const int t = threadIdx.x, w = t >> 6, l = t & 63;
  const int m0 = blockIdx.x * 64 + w * 16;
  const float mc = __int_as_float(*maxcs);

  ushort4 hv[16];
  float thv[16];
  u32 wtot = 0;
  // pass 1: load row, wave-max, threshold, count qualifiers
#pragma unroll
  for (int i = 0; i < 16; ++i) {
    int m = m0 + i;
    hv[i] = *(const ushort4*)&lmax[(size_t)m * 256 + l * 4];
    float v0 = __half2float(__ushort_as_half(hv[i].x));
    float v1 = __half2float(__ushort_as_half(hv[i].y));
    float v2 = __half2float(__ushort_as_half(hv[i].z));
    float v3 = __half2float(__ushort_as_half(hv[i].w));
    float g = fmaxf(fmaxf(v0, v1), fmaxf(v2, v3));
#pragma unroll
    for (int off = 1; off < 64; off <<= 1) g = fmaxf(g, __shfl_xor(g, off, 64));
    // rigorous margin: 2*(bf16 dot err bound 2*2^-7*sqrt(xsq*csq)) + fp16 slack
    float th = g - (0.033f * sqrtf(xsq[m] * mc) + 0.6f);
    thv[i] = th;
    wtot += __popcll(__ballot(v0 >= th));
    wtot += __popcll(__ballot(v1 >= th));
    wtot += __popcll(__ballot(v2 >= th));
    wtot += __popcll(__ballot(v3 >= th));
  }
  if (l == 0) wcnt[w] = wtot;
  __syncthreads();
  if (t == 0) gbase_s = atomicAdd(cnt, wcnt[0] + wcnt[1] + wcnt[2] + wcnt[3]);
  __syncthreads();
  u32 off = gbase_s;
  for (int ww = 0; ww < w; ++ww) off += wcnt[ww];
  // pass 2: write entries at deterministic ballot-prefix positions
#pragma unroll
  for (int i = 0; i < 16; ++i) {
    int m = m0 + i;
    float th = thv[i];
    float v[4];
    v[0] = __half2float(__ushort_as_half(hv[i].x));
    v[1] = __half2float(__ushort_as_half(hv[i].y));
    v[2] = __half2float(__ushort_as_half(hv[i].z));
    v[3] = __half2float(__ushort_as_half(hv[i].w));
#pragma unroll
    for (int j = 0; j < 4; ++j) {
      u64 mask = __ballot(v[j] >= th);
      if (v[j] >= th) {
        u32 pos = off + (u32)__popcll(mask & ((1ull << l) - 1ull));
        if (pos < LIST_CAP) list[pos] = ((u32)m << 8) | (u32)(l * 4 + j);
      }
      off += (u32)__popcll(mask);
    }
  }
}

// exact fp32 rescore of qualifying 32-code blocks; one wave per entry.
// Restructured (round 6): 8 lanes per code x 8 codes in parallel — breaks the
// serial 32x{L2-load -> 6-level reduce} chain that made round 5 latency-bound.
// Mirrors numpy op order incl. sqrt; key packs (dist_bits, ~k) => first-max-wins.
__global__ void __launch_bounds__(256)
vq_rescore(const u32* __restrict__ list, const u32* __restrict__ cnt,
           const float* __restrict__ xtf, const float* __restrict__ cb,
           const float* __restrict__ xsq, const float* __restrict__ csq,
           u64* __restrict__ keys) {
  u32 n = *cnt; if (n > LIST_CAP) n = LIST_CAP;
  const int l = threadIdx.x & 63;
  const int u = l & 7;          // lane within 8-lane group
  const int g = l >> 3;         // group 0..7 (one code each)
  int wid = (blockIdx.x * 256 + threadIdx.x) >> 6;
  int nw = (gridDim.x * 256) >> 6;
  for (u32 e = wid; e < n; e += nw) {
    u32 ent = list[e];
    int m = (int)(ent >> 8), blk = (int)(ent & 255u);
    // preload x row chunks for this lane (elements (i*8+u)*4 .. +3)
    float4 xv[8];
#pragma unroll
    for (int i = 0; i < 8; ++i)
      xv[i] = *(const float4*)&xtf[(size_t)m * C_ + (i * 8 + u) * 4];
    float xq = xsq[m];
    u64 bestkey = 0;
#pragma unroll
    for (int cc = 0; cc < 4; ++cc) {
      int k = blk * 32 + cc * 8 + g;
      const float* crow = &cb[(size_t)k * C_];
      float p = 0.0f;
#pragma unroll
      for (int i = 0; i < 8; ++i) {
        float4 cv = *(const float4*)&crow[(i * 8 + u) * 4];
        p += xv[i].x * cv.x + xv[i].y * cv.y + xv[i].z * cv.z + xv[i].w * cv.w;
      }
#pragma unroll
      for (int off = 1; off < 8; off <<= 1) p += __shfl_xor(p, off, 64);
      if (u == 0) {
        // exact reference op order: (x_sq + c_sq) - 2*dot, clamp, sqrt
        float d2 = __fsub_rn(__fadd_rn(xq, csq[k]), __fmul_rn(2.0f, p));
        float dist = sqrtf(fmaxf(d2, 0.0f));
        u64 key = ((u64)__float_as_uint(dist) << 32) |
                  (u64)(0xFFFFFFFFu - (u32)k);
        if (key > bestkey) bestkey = key;   // max dist, tie -> smaller k
      }
    }
    // cross-group max (leaders hold keys; others hold 0)
#pragma unroll
    for (int off = 8; off < 64; off <<= 1) {
      u64 o = __shfl_xor(bestkey, off, 64);
      if (o > bestkey) bestkey = o;
    }
    if (l == 0) atomicMax(&keys[m], bestkey);
  }
}

// ---------------- outputs ----------------

__global__ void vq_code(const u64* __restrict__ keys, float* __restrict__ out) {
  int m = blockIdx.x * 256 + threadIdx.x;
  u32 k = 0xFFFFFFFFu - (u32)(keys[m] & 0xFFFFFFFFull);
  out[m] = (float)k;
}

__global__ void __launch_bounds__(256)
vq_gather(const u64* __restrict__ keys, const float* __restrict__ cb,
          const float* __restrict__ x, float* __restrict__ emb,
          float* __restrict__ loss_acc) {
  __shared__ float rows[32 * 260];
  __shared__ int codes_s[32];
  __shared__ float partial[4];
  int t = threadIdx.x;
  int b = blockIdx.x >> 6;
  int l0 = (blockIdx.x & 63) * 32;
  if (t < 32) {
    u64 key = keys[b * L_ + l0 + t];
    codes_s[t] = (int)(0xFFFFFFFFu - (u32)(key & 0xFFFFFFFFull));
  }
  __syncthreads();
  {
    int r = t >> 3, c4 = t & 7;
    const float* src = cb + (size_t)codes_s[r] * C_;
#pragma unroll
    for (int j = 0; j < 8; ++j) {
      float4 v = *(const float4*)&src[(c4 + 8 * j) * 4];
      *(float4*)&rows[r * 260 + (c4 + 8 * j) * 4] = v;
    }
  }
  __syncthreads();
  float ls = 0.0f;
  int l = t & 31, cg = t >> 5;
#pragma unroll 4
  for (int cs = 0; cs < 32; ++cs) {
    int c = cg * 32 + cs;
    float v = rows[l * 260 + c];
    size_t gi = (size_t)(b * C_ + c) * L_ + l0 + l;
    emb[gi] = v;
    float d = x[gi] - v;
    ls = fmaf(d, d, ls);
  }
#pragma unroll
  for (int off = 1; off < 64; off <<= 1) ls += __shfl_xor(ls, off, 64);
  if ((t & 63) == 0) partial[t >> 6] = ls;
  __syncthreads();
  if (t == 0)
    atomicAdd(loss_acc, partial[0] + partial[1] + partial[2] + partial[3]);
}

__global__ void vq_loss(const float* __restrict__ loss_acc, float* __restrict__ out) {
  out[0] = loss_acc[0] / 4194304.0f;
}

extern "C" void kernel_launch(void* const* d_in, const int* in_sizes, int n_in,
                              void* d_out, int out_size, void* d_ws, size_t ws_size,
                              hipStream_t stream) {
  const float* x  = (const float*)d_in[0];   // (8, 256, 2048)
  const float* cb = (const float*)d_in[1];   // (8192, 256)
  float* out = (float*)d_out;                // [code(16384) | emb(4194304) | loss(1)]
  char* ws = (char*)d_ws;

  u64* keys      = (u64*)(ws + WS_KEYS);
  u32* cnt       = (u32*)(ws + WS_CNT);
  int* maxcs     = (int*)(ws + WS_MAXCS);
  float* loss_a  = (float*)(ws + WS_LOSS);
  float* xsq     = (float*)(ws + WS_XSQ);
  float* csq     = (float*)(ws + WS_CSQ);
  u32* list      = (u32*)(ws + WS_LIST);
  __half* lmax   = (__half*)(ws + WS_LMAX);
  ushort_t* xth  = (ushort_t*)(ws + WS_XTH);
  ushort_t* cbh  = (ushort_t*)(ws + WS_CBH);
  float* xtf     = out + M_;                 // emb region doubles as fp32 x^T scratch

  hipMemsetAsync(ws, 0, 131084, stream);     // keys + cnt + maxcs + loss

  vq_transpose<<<1024, 256, 0, stream>>>(x, xtf, xth);
  vq_cbprep<<<K_ / 16, 256, 0, stream>>>(cb, csq, maxcs, cbh);
  vq_xsqt<<<M_ / 16, 256, 0, stream>>>(xtf, xsq);
  vq_gemm<<<256, 512, 0, stream>>>(xth, cbh, csq, lmax);
  vq_thr<<<256, 256, 0, stream>>>(lmax, xsq, maxcs, list, cnt);
  vq_rescore<<<2048, 256, 0, stream>>>(list, cnt, xtf, cb, xsq, csq, keys);
  vq_code<<<M_ / 256, 256, 0, stream>>>(keys, out);
  vq_gather<<<(B_ * L_) / 32, 256, 0, stream>>>(keys, cb, x, out + M_, loss_a);
  vq_loss<<<1, 1, 0, stream>>>(loss_a, out + M_ + (size_t)B_ * C_ * L_);
}